// Round 2
// baseline (1219.457 us; speedup 1.0000x reference)
//
#include <hip/hip_runtime.h>
#include <hip/hip_bf16.h>

#define HID 100
#define TT 750
#define NBT 1024
#define ALPHA 0.01f
#define NSTD 0.1f

typedef __bf16 bf16x8 __attribute__((ext_vector_type(8)));
typedef float floatx4 __attribute__((ext_vector_type(4)));

__device__ __forceinline__ float fast_tanh(float v) {
    // tanh(v) = 1 - 2/(exp(2v)+1); monotone, graceful at +-inf, abs err ~1e-6
    float e = __expf(2.0f * v);
    return 1.0f - 2.0f / (e + 1.0f);
}

__global__ __launch_bounds__(256, 1)
void rnn_kernel(const float* __restrict__ useq,   // [750][1024][4]
                const float* __restrict__ noise,  // [750][1024][100]
                const float* __restrict__ Jw,     // [100][100]
                const float* __restrict__ Bm,     // [4][100]
                const float* __restrict__ cxp,    // [100]
                const float* __restrict__ Ww,     // [100]
                const float* __restrict__ Wb,     // [1]
                float* __restrict__ out)          // [1024]
{
    // double-buffered r: [parity][16 rows (M=batch) x 128 bf16 (K=h)], XOR-swizzled chunks
    __shared__ __align__(16) __bf16 rbuf[2][16 * 128];
    __shared__ float red[4][8][16];   // epilogue: [batch][tile][lane]

    const int tid  = threadIdx.x;
    const int wv   = tid >> 6;
    const int lane = tid & 63;
    const int m16  = lane & 15;
    const int q    = lane >> 4;
    const int wg   = blockIdx.x;
    const int gb0  = wg * 4;          // 4 global batches per WG

    // zero both r buffers (rows 4..15 and k>=100 stay zero forever; r_0 = 0) and red
    {
        floatx4 z = {0.f, 0.f, 0.f, 0.f};
        ((floatx4*)rbuf)[tid]       = z;
        ((floatx4*)rbuf)[tid + 256] = z;
        ((float*)red)[tid]       = 0.f;
        ((float*)red)[tid + 256] = 0.f;
    }

    // ---- J fragments (B-operand layout), hi/lo bf16 split; wave owns N-tiles {2wv, 2wv+1} ----
    bf16x8 jhi[2][4], jlo[2][4];
    #pragma unroll
    for (int ti = 0; ti < 2; ++ti) {
        const int tile = wv * 2 + ti;
        const int h = tile * 16 + m16;          // B n-index -> J row h
        #pragma unroll
        for (int s = 0; s < 4; ++s) {
            bf16x8 vhi, vlo;
            #pragma unroll
            for (int j = 0; j < 8; ++j) {
                const int k = s * 32 + q * 8 + j;
                float v = (h < HID && k < HID) ? Jw[h * HID + k] : 0.0f;
                __bf16 hi = (__bf16)v;
                vhi[j] = hi;
                vlo[j] = (__bf16)(v - (float)hi);
            }
            jhi[ti][s] = vhi;
            jlo[ti][s] = vlo;
        }
    }

    // ---- per-lane update-side constants (active lanes: q==0, valid h) ----
    int   hv[2];
    bool  val[2];
    float bmv[2][4], cxv[2], wwv[2];
    #pragma unroll
    for (int ti = 0; ti < 2; ++ti) {
        const int tile = wv * 2 + ti;
        const int h = tile * 16 + m16;
        hv[ti]  = h;
        val[ti] = (q == 0) && (h < HID);
        if (val[ti]) {
            bmv[ti][0] = Bm[0*HID + h]; bmv[ti][1] = Bm[1*HID + h];
            bmv[ti][2] = Bm[2*HID + h]; bmv[ti][3] = Bm[3*HID + h];
            cxv[ti] = cxp[h];
            wwv[ti] = Ww[h];
        } else {
            bmv[ti][0]=bmv[ti][1]=bmv[ti][2]=bmv[ti][3]=0.f; cxv[ti]=0.f; wwv[ti]=0.f;
        }
    }

    // ---- prefetch (depth 2) ----
    float   nA[2][4], nB[2][4];
    floatx4 uA[4], uB[4];
    auto pfN = [&](int t, float (&N)[2][4]) {
        #pragma unroll
        for (int ti = 0; ti < 2; ++ti) {
            if (val[ti]) {
                const float* p = noise + (size_t)t * (NBT * HID) + (size_t)gb0 * HID + hv[ti];
                #pragma unroll
                for (int b = 0; b < 4; ++b) N[ti][b] = p[b * HID];
            }
        }
    };
    auto pfU = [&](int t, floatx4 (&U)[4]) {
        const floatx4* p = (const floatx4*)(useq + (size_t)t * (NBT * 4) + (size_t)gb0 * 4);
        #pragma unroll
        for (int b = 0; b < 4; ++b) U[b] = p[b];
    };
    pfN(0, nA); pfU(0, uA);
    pfN(1, nB); pfU(1, uB);

    float x[2][4] = {{0.f,0.f,0.f,0.f},{0.f,0.f,0.f,0.f}};
    __syncthreads();

    auto step = [&](int t, int pb, float (&N)[2][4], floatx4 (&U)[4]) {
        // ---- A-frags of r_t from rbuf[pb] ----
        const bf16x8* rb = (const bf16x8*)(rbuf[pb]);
        bf16x8 afr[4];
        #pragma unroll
        for (int s = 0; s < 4; ++s)
            afr[s] = rb[m16 * 16 + ((s * 4 + q) ^ (lane & 7))];
        // ---- y_t = r_t @ (Jhi+Jlo)^T ----
        floatx4 ys[2];
        #pragma unroll
        for (int ti = 0; ti < 2; ++ti) {
            floatx4 ah = {0.f,0.f,0.f,0.f}, al = {0.f,0.f,0.f,0.f};
            #pragma unroll
            for (int s = 0; s < 4; ++s)
                ah = __builtin_amdgcn_mfma_f32_16x16x32_bf16(afr[s], jhi[ti][s], ah, 0, 0, 0);
            #pragma unroll
            for (int s = 0; s < 4; ++s)
                al = __builtin_amdgcn_mfma_f32_16x16x32_bf16(afr[s], jlo[ti][s], al, 0, 0, 0);
            ys[ti] = ah + al;
        }
        // ---- in-register update (lanes q==0): x per (tile, batch=reg) ----
        __bf16* wbuf = rbuf[pb ^ 1];
        #pragma unroll
        for (int ti = 0; ti < 2; ++ti) {
            if (val[ti]) {
                #pragma unroll
                for (int b = 0; b < 4; ++b) {
                    const float d = U[b][0]*bmv[ti][0] + U[b][1]*bmv[ti][1]
                                  + U[b][2]*bmv[ti][2] + U[b][3]*bmv[ti][3];
                    x[ti][b] = x[ti][b] * (1.0f - ALPHA)
                             + ALPHA * (ys[ti][b] + d + cxv[ti] + NSTD * N[ti][b]);
                    const float r = fast_tanh(x[ti][b]);
                    wbuf[b * 128 + (((hv[ti] >> 3) ^ b) << 3) + (hv[ti] & 7)] = (__bf16)r;
                }
            }
        }
        // ---- prefetch t+2 into the just-consumed registers ----
        int tf = t + 2; if (tf > TT - 1) tf = TT - 1;
        pfN(tf, N); pfU(tf, U);
        __syncthreads();
    };

    for (int t2 = 0; t2 < TT; t2 += 2) {
        step(t2,     0, nA, uA);
        step(t2 + 1, 1, nB, uB);
    }

    // ---- epilogue: out[b] = Wb + sum_h tanh(x_final[b][h]) * Ww[h] ----
    #pragma unroll
    for (int ti = 0; ti < 2; ++ti) {
        if (val[ti]) {
            #pragma unroll
            for (int b = 0; b < 4; ++b)
                red[b][wv * 2 + ti][m16] = fast_tanh(x[ti][b]) * wwv[ti];
        }
    }
    __syncthreads();
    if (tid < 4) {
        float s = Wb[0];
        #pragma unroll 8
        for (int j = 0; j < 112; ++j) s += red[tid][j >> 4][j & 15];
        out[gb0 + tid] = s;
    }
}

extern "C" void kernel_launch(void* const* d_in, const int* in_sizes, int n_in,
                              void* d_out, int out_size, void* d_ws, size_t ws_size,
                              hipStream_t stream) {
    rnn_kernel<<<dim3(256), dim3(256), 0, stream>>>(
        (const float*)d_in[0], (const float*)d_in[1], (const float*)d_in[2],
        (const float*)d_in[3], (const float*)d_in[4], (const float*)d_in[5],
        (const float*)d_in[6], (float*)d_out);
}

// Round 3
// 881.300 us; speedup vs baseline: 1.3837x; 1.3837x over previous
//
#include <hip/hip_runtime.h>
#include <hip/hip_bf16.h>

#define HID 100
#define TT 750
#define NBT 1024
#define ALPHA 0.01f
#define NSTD 0.1f

typedef __bf16 bf16x8 __attribute__((ext_vector_type(8)));
typedef __bf16 bf16x4 __attribute__((ext_vector_type(4)));
typedef float floatx4 __attribute__((ext_vector_type(4)));

__device__ __forceinline__ float fast_tanh(float v) {
    // tanh(v) = 1 - 2/(exp(2v)+1); monotone, graceful at +-inf
    float e = __expf(2.0f * v);
    return 1.0f - 2.0f / (e + 1.0f);
}

// 7 waves/WG: wave wv owns N-tile wv (h = wv*16 + m16). 4 batches/WG in M-rows
// {0,4,8,12}; C-layout row = q*4 + reg => lane (q,m16) gets y[batch q][h] in reg 0.
// K-slots 100..108 of the MFMA carry the input drive and c_x:
//   A: k100-103 = u_hi, k104-107 = u_lo, k108 = 1.0
//   Bhi: k100-103 = Bm_hi, k104-107 = Bm_hi, k108 = cx_hi
//   Blo: k100-103 = Bm_lo, k104-107 = 0,     k108 = cx_lo
__global__ __launch_bounds__(448, 2)
void rnn_kernel(const float* __restrict__ useq,   // [750][1024][4]
                const float* __restrict__ noise,  // [750][1024][100]
                const float* __restrict__ Jw,     // [100][100]
                const float* __restrict__ Bm,     // [4][100]
                const float* __restrict__ cxp,    // [100]
                const float* __restrict__ Ww,     // [100]
                const float* __restrict__ Wb,     // [1]
                float* __restrict__ out)          // [1024]
{
    // r/A double buffer: 4 storage rows (batch) x 128 bf16 (K), 16B chunks
    // XOR-swizzled by (batch<<2) so the 16 active reader lanes land <=2-way.
    __shared__ __align__(16) __bf16 abuf[2][4 * 128];
    __shared__ float red[4][112];

    const int tid  = threadIdx.x;
    const int wv   = tid >> 6;
    const int lane = tid & 63;
    const int m16  = lane & 15;
    const int q    = lane >> 4;          // batch index 0..3
    const int h    = wv * 16 + m16;      // hidden index 0..111
    const bool act = (h < HID);
    const int gb0  = blockIdx.x * 4;     // 4 global batches per WG

    // ---- zero A-buffers (rows hold r=tanh(0)=0 for t=0; pads stay 0) ----
    if (tid < 128) ((floatx4*)abuf)[tid] = floatx4{0.f, 0.f, 0.f, 0.f};

    // ---- J/Bm/cx fragments (B-operand layout), hi + lo residual: 32 VGPR ----
    bf16x8 jhi[4], jlo[4];
    #pragma unroll
    for (int s = 0; s < 4; ++s) {
        bf16x8 vh = {}; bf16x8 vl = {};
        #pragma unroll
        for (int j = 0; j < 8; ++j) {
            const int k = s * 32 + q * 8 + j;
            float a = 0.f; bool lo = false;
            if (act) {
                if (k < HID)        { a = Jw[h * HID + k];        lo = true; }
                else if (k < 104)   { a = Bm[(k - 100) * HID + h]; lo = true; }
                else if (k < 108)   { a = Bm[(k - 104) * HID + h]; lo = false; }
                else if (k == 108)  { a = cxp[h];                  lo = true; }
            }
            const __bf16 hi = (__bf16)a;
            vh[j] = hi;
            vl[j] = lo ? (__bf16)(a - (float)hi) : (__bf16)0.f;
        }
        jhi[s] = vh; jlo[s] = vl;
    }

    __syncthreads();   // zeroing visible before staging writes

    // ---- stage u(0) + constant-1.0 slots ----
    if (tid < 4) {
        const floatx4 u0 = *(const floatx4*)(useq + (size_t)(gb0 + tid) * 4);
        bf16x4 uh, ul;
        #pragma unroll
        for (int i = 0; i < 4; ++i) {
            const __bf16 hi = (__bf16)u0[i];
            uh[i] = hi; ul[i] = (__bf16)(u0[i] - (float)hi);
        }
        *(bf16x4*)&abuf[0][tid * 128 + ((12 ^ (tid << 2)) << 3) + 4] = uh;
        *(bf16x4*)&abuf[0][tid * 128 + ((13 ^ (tid << 2)) << 3)]     = ul;
        abuf[0][tid * 128 + ((13 ^ (tid << 2)) << 3) + 4] = (__bf16)1.0f;
        abuf[1][tid * 128 + ((13 ^ (tid << 2)) << 3) + 4] = (__bf16)1.0f;
    }

    // ---- register prefetch pipelines, depth 4 ----
    const float* nptr = noise + (size_t)(gb0 + q) * HID + h;   // + t*NBT*HID
    float n0 = 0.f, n1 = 0.f, n2 = 0.f, n3 = 0.f;
    if (act) {
        n0 = nptr[(size_t)0 * NBT * HID];
        n1 = nptr[(size_t)1 * NBT * HID];
        n2 = nptr[(size_t)2 * NBT * HID];
        n3 = nptr[(size_t)3 * NBT * HID];
    }
    floatx4 us0 = {}, us1 = {}, us2 = {}, us3 = {};  // us{j} holds u(t'), t' = j mod 4
    if (tid < 4) {
        us1 = *(const floatx4*)(useq + (size_t)1 * NBT * 4 + (gb0 + tid) * 4);
        us2 = *(const floatx4*)(useq + (size_t)2 * NBT * 4 + (gb0 + tid) * 4);
        us3 = *(const floatx4*)(useq + (size_t)3 * NBT * 4 + (gb0 + tid) * 4);
        us0 = *(const floatx4*)(useq + (size_t)4 * NBT * 4 + (gb0 + tid) * 4);
    }

    float x = 0.f;
    __syncthreads();   // one-time full barrier before steady loop

    auto body = [&](int t, int p, float& nr, floatx4& ur) {
        // A-fragments of r_t (+u slots) from abuf[p]; only rows {0,4,8,12} real
        const int br = m16 >> 2;
        bf16x8 afr[4];
        #pragma unroll
        for (int s = 0; s < 4; ++s) {
            bf16x8 a = {};
            if ((m16 & 3) == 0)
                a = *(const bf16x8*)&abuf[p][br * 128 + ((((s << 2) | q) ^ (br << 2)) << 3)];
            afr[s] = a;
        }
        floatx4 ah = {0.f,0.f,0.f,0.f}, al = {0.f,0.f,0.f,0.f};
        #pragma unroll
        for (int s = 0; s < 4; ++s)
            ah = __builtin_amdgcn_mfma_f32_16x16x32_bf16(afr[s], jhi[s], ah, 0, 0, 0);
        #pragma unroll
        for (int s = 0; s < 4; ++s)
            al = __builtin_amdgcn_mfma_f32_16x16x32_bf16(afr[s], jlo[s], al, 0, 0, 0);
        const float y = ah[0] + al[0];   // row 4q, reg 0 = (batch q, h)

        // stage u(t+1) bf16 hi/lo into abuf[p^1], then refill with u(t+5)
        if (tid < 4) {
            bf16x4 uh, ul;
            #pragma unroll
            for (int i = 0; i < 4; ++i) {
                const __bf16 hi = (__bf16)ur[i];
                uh[i] = hi; ul[i] = (__bf16)(ur[i] - (float)hi);
            }
            *(bf16x4*)&abuf[p ^ 1][tid * 128 + ((12 ^ (tid << 2)) << 3) + 4] = uh;
            *(bf16x4*)&abuf[p ^ 1][tid * 128 + ((13 ^ (tid << 2)) << 3)]     = ul;
            const int tu = (t + 5 <= TT - 1) ? (t + 5) : (TT - 1);
            ur = *(const floatx4*)(useq + (size_t)tu * NBT * 4 + (gb0 + tid) * 4);
        }

        // in-register state update; write r_{t+1} into abuf[p^1]; refill noise
        if (act) {
            x = x * (1.f - ALPHA) + ALPHA * (y + NSTD * nr);
            const float r = fast_tanh(x);
            abuf[p ^ 1][q * 128 + (((h >> 3) ^ (q << 2)) << 3) + (h & 7)] = (__bf16)r;
            const int tn = (t + 4 <= TT - 1) ? (t + 4) : (TT - 1);
            nr = nptr[(size_t)tn * NBT * HID];
        }

        // raw barrier: drain LDS (cross-wave r/u exchange) but NOT vmcnt —
        // global prefetches are wave-private and stay in flight.
        asm volatile("s_waitcnt lgkmcnt(0)\n\ts_barrier" ::: "memory");
    };

    for (int t4 = 0; t4 < 748; t4 += 4) {
        body(t4 + 0, 0, n0, us1);
        body(t4 + 1, 1, n1, us2);
        body(t4 + 2, 0, n2, us3);
        body(t4 + 3, 1, n3, us0);
    }
    body(748, 0, n0, us1);
    body(749, 1, n1, us2);

    // ---- epilogue: out[b] = Wb + sum_h tanh(x_final) * Ww[h] ----
    if (act) red[q][h] = fast_tanh(x) * Ww[h];
    __syncthreads();
    if (tid < 4) {
        float s = Wb[0];
        #pragma unroll 4
        for (int i = 0; i < HID; ++i) s += red[tid][i];
        out[gb0 + tid] = s;
    }
}

extern "C" void kernel_launch(void* const* d_in, const int* in_sizes, int n_in,
                              void* d_out, int out_size, void* d_ws, size_t ws_size,
                              hipStream_t stream) {
    rnn_kernel<<<dim3(256), dim3(448), 0, stream>>>(
        (const float*)d_in[0], (const float*)d_in[1], (const float*)d_in[2],
        (const float*)d_in[3], (const float*)d_in[4], (const float*)d_in[5],
        (const float*)d_in[6], (float*)d_out);
}

// Round 4
// 827.708 us; speedup vs baseline: 1.4733x; 1.0647x over previous
//
#include <hip/hip_runtime.h>
#include <hip/hip_bf16.h>

#define HID 100
#define TT 750
#define NBT 1024
#define ALPHA 0.01f
#define NSTD 0.1f

typedef __bf16 bf16x8 __attribute__((ext_vector_type(8)));
typedef float floatx4 __attribute__((ext_vector_type(4)));

__device__ __forceinline__ float fast_tanh(float v) {
    // tanh(v) = 1 - 2/(exp(2v)+1); monotone, graceful at +-inf
    float e = __expf(2.0f * v);
    return 1.0f - 2.0f / (e + 1.0f);
}

#define MFMA(A, B, C) __builtin_amdgcn_mfma_f32_16x16x32_bf16((A), (B), (C), 0, 0, 0)

// 7 waves/WG; wave wv owns N-tile wv (h = wv*16 + m16). 4 batches/WG in M-rows
// {0,4,8,12} (batch = q = lane>>4); C-layout row = q*4 + reg => lane (q,m16)
// gets y[batch q][h] in acc reg 0. Drive d = cx + u.B + 0.1*n rides in the
// MFMA C operand ({d,0,0,0}), so no LDS staging of u and no K-extension.
__global__ __launch_bounds__(448)
void rnn_kernel(const float* __restrict__ useq,   // [750][1024][4]
                const float* __restrict__ noise,  // [750][1024][100]
                const float* __restrict__ Jw,     // [100][100]
                const float* __restrict__ Bm,     // [4][100]
                const float* __restrict__ cxp,    // [100]
                const float* __restrict__ Ww,     // [100]
                const float* __restrict__ Wb,     // [1]
                float* __restrict__ out)          // [1024]
{
    // r double buffer in full A-layout: 16 rows x 128 bf16, rows 1-3,5-7,...
    // and cols >=100 permanently zero => branch-free b128 reads on all lanes.
    // 16B chunks XOR-swizzled by (row & 7) for even bank spread.
    __shared__ __align__(16) __bf16 abuf[2][16][128];
    __shared__ float red[4][112];

    const int tid  = threadIdx.x;
    const int wv   = tid >> 6;
    const int lane = tid & 63;
    const int m16  = lane & 15;
    const int q    = lane >> 4;          // batch index 0..3
    const int h    = wv * 16 + m16;      // hidden index 0..111
    const bool act = (h < HID);
    const int gb0  = blockIdx.x * 4;

    // ---- zero both A buffers (r_0 = tanh(0) = 0; pad rows/cols stay 0) ----
    for (int i = tid; i < 512; i += 448)
        ((floatx4*)abuf)[i] = floatx4{0.f, 0.f, 0.f, 0.f};

    // ---- J fragments (B-operand layout), hi + bf16-residual lo: 32 VGPR ----
    bf16x8 jhi[4], jlo[4];
    #pragma unroll
    for (int s = 0; s < 4; ++s) {
        bf16x8 vh = {}; bf16x8 vl = {};
        #pragma unroll
        for (int j = 0; j < 8; ++j) {
            const int k = s * 32 + q * 8 + j;
            float a = (act && k < HID) ? Jw[h * HID + k] : 0.0f;
            const __bf16 hi = (__bf16)a;
            vh[j] = hi;
            vl[j] = (__bf16)(a - (float)hi);
        }
        jhi[s] = vh; jlo[s] = vl;
    }

    // ---- per-lane update-side constants ----
    float bm0=0.f, bm1=0.f, bm2=0.f, bm3=0.f, cx=0.f;
    if (act) {
        bm0 = Bm[0*HID + h]; bm1 = Bm[1*HID + h];
        bm2 = Bm[2*HID + h]; bm3 = Bm[3*HID + h];
        cx  = cxp[h];
    }

    // ---- register prefetch pipelines: noise depth 4, u depth 2 ----
    const float* nptr = noise + (size_t)(gb0 + q) * HID + (act ? h : (HID - 1));
    const floatx4* uptr = (const floatx4*)(useq + (size_t)(gb0 + q) * 4);
    float n0=0.f, n1=0.f, n2=0.f, n3=0.f;
    if (act) {
        n0 = nptr[(size_t)0 * NBT * HID];
        n1 = nptr[(size_t)1 * NBT * HID];
        n2 = nptr[(size_t)2 * NBT * HID];
        n3 = nptr[(size_t)3 * NBT * HID];
    }
    floatx4 u0 = uptr[(size_t)0 * NBT];
    floatx4 u1 = uptr[(size_t)1 * NBT];

    // LDS element offsets (loop-invariant): read chunks (4s+q)^(m16&7) of row
    // m16; write element h of row 4q with the same swizzle.
    int rdo[4];
    #pragma unroll
    for (int s = 0; s < 4; ++s)
        rdo[s] = m16 * 128 + (((4 * s + q) ^ (m16 & 7)) << 3);
    const int wro = (4 * q) * 128 + ((((h >> 3) ^ ((4 * q) & 7)) << 3) | (h & 7));

    float x = 0.f;
    const floatx4 kz = {0.f, 0.f, 0.f, 0.f};
    __syncthreads();

    auto body = [&](int t, int p, float& nr, floatx4& ur) {
        // drive (fp32, off the LDS path): rides into the MFMA C operand
        const float d = cx + ur[0]*bm0 + ur[1]*bm1 + ur[2]*bm2 + ur[3]*bm3
                      + NSTD * nr;
        floatx4 c0 = kz; c0[0] = d;

        // A-fragments of r_t: branch-free (pad rows read zeros)
        const __bf16* ab = &abuf[p][0][0];
        bf16x8 afr[4];
        #pragma unroll
        for (int s = 0; s < 4; ++s)
            afr[s] = *(const bf16x8*)(ab + rdo[s]);

        // four independent 2-chains; y includes the drive via c0
        floatx4 ah0 = MFMA(afr[1], jhi[1], MFMA(afr[0], jhi[0], c0));
        floatx4 ah1 = MFMA(afr[3], jhi[3], MFMA(afr[2], jhi[2], kz));
        floatx4 al0 = MFMA(afr[1], jlo[1], MFMA(afr[0], jlo[0], kz));
        floatx4 al1 = MFMA(afr[3], jlo[3], MFMA(afr[2], jlo[2], kz));
        const float y = (ah0[0] + ah1[0]) + (al0[0] + al1[0]);

        // state update + r write + noise refill (active lanes only)
        if (act) {
            x = x * (1.f - ALPHA) + ALPHA * y;
            const float r = fast_tanh(x);
            abuf[p ^ 1][0][wro] = (__bf16)r;
            const int tn = (t + 4 <= TT - 1) ? (t + 4) : (TT - 1);
            nr = nptr[(size_t)tn * NBT * HID];
        }
        // u refill, depth 2 (all lanes; broadcast within q-group)
        {
            const int tu = (t + 2 <= TT - 1) ? (t + 2) : (TT - 1);
            ur = uptr[(size_t)tu * NBT];
        }
        // barrier draining LDS only; global prefetches stay in flight
        asm volatile("s_waitcnt lgkmcnt(0)\n\ts_barrier" ::: "memory");
    };

    for (int t4 = 0; t4 < 748; t4 += 4) {
        body(t4 + 0, 0, n0, u0);
        body(t4 + 1, 1, n1, u1);
        body(t4 + 2, 0, n2, u0);
        body(t4 + 3, 1, n3, u1);
    }
    body(748, 0, n0, u0);
    body(749, 1, n1, u1);

    // ---- epilogue: out[b] = Wb + sum_h tanh(x_final) * Ww[h] ----
    if (act) red[q][h] = fast_tanh(x) * Ww[h];
    __syncthreads();
    if (tid < 4) {
        float s = Wb[0];
        #pragma unroll 4
        for (int i = 0; i < HID; ++i) s += red[tid][i];
        out[gb0 + tid] = s;
    }
}

extern "C" void kernel_launch(void* const* d_in, const int* in_sizes, int n_in,
                              void* d_out, int out_size, void* d_ws, size_t ws_size,
                              hipStream_t stream) {
    rnn_kernel<<<dim3(256), dim3(448), 0, stream>>>(
        (const float*)d_in[0], (const float*)d_in[1], (const float*)d_in[2],
        (const float*)d_in[3], (const float*)d_in[4], (const float*)d_in[5],
        (const float*)d_in[6], (float*)d_out);
}

// Round 5
// 765.266 us; speedup vs baseline: 1.5935x; 1.0816x over previous
//
#include <hip/hip_runtime.h>
#include <hip/hip_bf16.h>

#define HID 100
#define TT 750
#define NBT 1024
#define ALPHA 0.01f
#define NSTD 0.1f

typedef __bf16 bf16x8 __attribute__((ext_vector_type(8)));
typedef float floatx4 __attribute__((ext_vector_type(4)));

__device__ __forceinline__ float fast_tanh(float v) {
    // tanh(v) = 1 - 2/(exp(2v)+1); monotone, graceful at +-inf
    float e = __expf(2.0f * v);
    return 1.0f - 2.0f / (e + 1.0f);
}

#define MFMA(A, B, C) __builtin_amdgcn_mfma_f32_16x16x32_bf16((A), (B), (C), 0, 0, 0)

// 512 WGs x 2 batches (=> 2 WGs/CU for chain-hiding TLP), 7 waves/WG.
// Wave wv owns N-tile wv (h = wv*16 + m16). Batches live in M-rows {0,1}:
// C-layout row = q*4 + reg, so q=0 lanes get y[b0][h] in reg 0 and y[b1][h]
// in reg 1; one ds_swizzle (xor16) hands y[b1] to the q=1 lanes so every
// active lane does exactly one update. A-reads are exec-masked to m16<2
// (rows 2..15 are zeros supplied by the mask, not by memory) => tiny LDS.
__global__ __launch_bounds__(448)
void rnn_kernel(const float* __restrict__ useq,   // [750][1024][4]
                const float* __restrict__ noise,  // [750][1024][100]
                const float* __restrict__ Jw,     // [100][100]
                const float* __restrict__ Bm,     // [4][100]
                const float* __restrict__ cxp,    // [100]
                const float* __restrict__ Ww,     // [100]
                const float* __restrict__ Wb,     // [1]
                float* __restrict__ out)          // [1024]
{
    // double-buffered r: [parity][2 rows (batch)][128 bf16 K]; 1 KB total
    __shared__ __align__(16) __bf16 abuf[2][2][128];
    __shared__ float red[2][112];

    const int tid  = threadIdx.x;
    const int wv   = tid >> 6;
    const int lane = tid & 63;
    const int m16  = lane & 15;
    const int q    = lane >> 4;
    const int h    = wv * 16 + m16;          // hidden index 0..111
    const bool act = (q < 2) && (h < HID);   // this lane updates (batch q, h)
    const int gb0  = blockIdx.x * 2;

    // zero r buffers (r_0 = tanh(0) = 0; cols >=100 stay 0 forever)
    if (tid < 64) ((floatx4*)abuf)[tid] = floatx4{0.f, 0.f, 0.f, 0.f};

    // ---- J fragments (B-operand layout), hi + bf16-residual lo: 32 VGPR ----
    bf16x8 jhi[4], jlo[4];
    #pragma unroll
    for (int s = 0; s < 4; ++s) {
        bf16x8 vh = {}; bf16x8 vl = {};
        #pragma unroll
        for (int j = 0; j < 8; ++j) {
            const int k = s * 32 + q * 8 + j;
            float a = (h < HID && k < HID) ? Jw[h * HID + k] : 0.0f;
            const __bf16 hi = (__bf16)a;
            vh[j] = hi;
            vl[j] = (__bf16)(a - (float)hi);
        }
        jhi[s] = vh; jlo[s] = vl;
    }

    // ---- per-lane update-side constants (depend on h only) ----
    float bm0=0.f, bm1=0.f, bm2=0.f, bm3=0.f, cx=0.f;
    if (act) {
        bm0 = Bm[0*HID + h]; bm1 = Bm[1*HID + h];
        bm2 = Bm[2*HID + h]; bm3 = Bm[3*HID + h];
        cx  = cxp[h];
    }

    // ---- register prefetch pipelines: noise depth 4, u depth 2 ----
    const float* nptr = noise + (size_t)(gb0 + (q & 1)) * HID + (act ? h : 0);
    const floatx4* uptr = (const floatx4*)(useq + (size_t)(gb0 + (q & 1)) * 4);
    float n0=0.f, n1=0.f, n2=0.f, n3=0.f;
    floatx4 u0 = {0,0,0,0}, u1 = {0,0,0,0};
    if (act) {
        n0 = nptr[(size_t)0 * NBT * HID];
        n1 = nptr[(size_t)1 * NBT * HID];
        n2 = nptr[(size_t)2 * NBT * HID];
        n3 = nptr[(size_t)3 * NBT * HID];
        u0 = uptr[(size_t)0 * NBT];
        u1 = uptr[(size_t)1 * NBT];
    }

    float x = 0.f;
    __syncthreads();

    auto body = [&](int t, int p, float& nr, floatx4& ur) {
        // A-fragments of r_t: rows 0,1 from LDS, rows 2..15 are masked zeros
        bf16x8 afr[4] = {{}, {}, {}, {}};
        if (m16 < 2) {
            const __bf16* ab = &abuf[p][0][0];
            #pragma unroll
            for (int s = 0; s < 4; ++s)
                afr[s] = *(const bf16x8*)(ab + m16 * 128 + (4 * s + q) * 8);
        }
        const floatx4 z = {0.f, 0.f, 0.f, 0.f};
        floatx4 ah0 = MFMA(afr[1], jhi[1], MFMA(afr[0], jhi[0], z));
        floatx4 ah1 = MFMA(afr[3], jhi[3], MFMA(afr[2], jhi[2], z));
        floatx4 al0 = MFMA(afr[1], jlo[1], MFMA(afr[0], jlo[0], z));
        floatx4 al1 = MFMA(afr[3], jlo[3], MFMA(afr[2], jlo[2], z));
        const float y0 = (ah0[0] + ah1[0]) + (al0[0] + al1[0]);
        const float y1 = (ah0[1] + ah1[1]) + (al0[1] + al1[1]);
        // hand batch-1's y to the q=1 lanes (xor-16 swizzle within 32-halves)
        const float y1s = __int_as_float(
            __builtin_amdgcn_ds_swizzle(__float_as_int(y1), 0x401F));
        const float y = (q == 0) ? y0 : y1s;

        if (act) {
            const float d = cx + ur[0]*bm0 + ur[1]*bm1 + ur[2]*bm2 + ur[3]*bm3
                          + NSTD * nr;
            x = x * (1.f - ALPHA) + ALPHA * (y + d);
            const float r = fast_tanh(x);
            abuf[p ^ 1][q][h] = (__bf16)r;
            const int tn = (t + 4 <= TT - 1) ? (t + 4) : (TT - 1);
            nr = nptr[(size_t)tn * NBT * HID];
            const int tu = (t + 2 <= TT - 1) ? (t + 2) : (TT - 1);
            ur = uptr[(size_t)tu * NBT];
        }
        // barrier draining LDS only; global prefetches stay in flight
        asm volatile("s_waitcnt lgkmcnt(0)\n\ts_barrier" ::: "memory");
    };

    for (int t4 = 0; t4 < 748; t4 += 4) {
        body(t4 + 0, 0, n0, u0);
        body(t4 + 1, 1, n1, u1);
        body(t4 + 2, 0, n2, u0);
        body(t4 + 3, 1, n3, u1);
    }
    body(748, 0, n0, u0);
    body(749, 1, n1, u1);

    // ---- epilogue: out[b] = Wb + sum_h tanh(x_final) * Ww[h] ----
    if (act) red[q][h] = fast_tanh(x) * Ww[h];
    __syncthreads();
    if (tid < 2) {
        float s = Wb[0];
        #pragma unroll 4
        for (int i = 0; i < HID; ++i) s += red[tid][i];
        out[gb0 + tid] = s;
    }
}

extern "C" void kernel_launch(void* const* d_in, const int* in_sizes, int n_in,
                              void* d_out, int out_size, void* d_ws, size_t ws_size,
                              hipStream_t stream) {
    rnn_kernel<<<dim3(512), dim3(448), 0, stream>>>(
        (const float*)d_in[0], (const float*)d_in[1], (const float*)d_in[2],
        (const float*)d_in[3], (const float*)d_in[4], (const float*)d_in[5],
        (const float*)d_in[6], (float*)d_out);
}